// Round 5
// baseline (380.625 us; speedup 1.0000x reference)
//
#include <hip/hip_runtime.h>

#define N_NODES 10000
#define N_EDGES 320000
#define NE_TOT  330000   /* E + N */
#define NEG_SLOPE 0.2f
#define LN_EPS 1e-5f

/* workspace layout (bytes) */
#define OFF_CNT    0u         /* int[N]            */
#define OFF_FILL   40000u     /* int[N]            */
#define OFF_ROWPTR 80128u     /* int[N+1]          */
#define OFF_EIDS   120320u    /* int[E+N]          */
#define OFF_POSE   1440512u   /* int[E+N]: CSR pos of edge id */
#define OFF_XLH    4000512u   /* ushort[N*256] bf16 */
#define OFF_XRH    9120512u   /* ushort[N*256] bf16 */
#define OFF_LOG    14240512u  /* float[(E+N)*4] logits fallback (len>256 only) */
#define OFF_WLF    19520512u  /* ushort[8192*8] bf16 Wl fragments */
#define OFF_WRF    19651584u  /* ushort[8192*8] bf16 Wr fragments */
#define OFF_WEF    19782656u  /* ushort[2048*8] bf16 We fragments */
#define OFF_SD     19815424u  /* int[E+N]: s | (d<<16), CSR order */
#define OFF_EAC    21135424u  /* ushort[(E+N)*64] bf16 edge_attr, CSR order */
#define OFF_EPC    63375424u  /* ushort[(E+N)*256] bf16 We-projection, CSR order */
/* end: 232335424 */

typedef __bf16 bf16x8 __attribute__((ext_vector_type(8)));
typedef float  f32x4  __attribute__((ext_vector_type(4)));
typedef unsigned short us4 __attribute__((ext_vector_type(4)));

__device__ __forceinline__ float bf2f(unsigned short u) {
    union { unsigned int i; float f; } v;
    v.i = ((unsigned int)u) << 16;
    return v.f;
}
/* packed bf16 halves of a dword -> f32: low = shift, high = single AND */
__device__ __forceinline__ float lo2f(unsigned int u) {
    union { unsigned int i; float f; } v;
    v.i = u << 16;
    return v.f;
}
__device__ __forceinline__ float hi2f(unsigned int u) {
    union { unsigned int i; float f; } v;
    v.i = u & 0xFFFF0000u;
    return v.f;
}
__device__ __forceinline__ unsigned short f2bf(float x) {
    __bf16 b = (__bf16)x;
    return __builtin_bit_cast(unsigned short, b);
}
__device__ __forceinline__ bf16x8 cvt8(const float* p) {
    float4 v0 = *reinterpret_cast<const float4*>(p);
    float4 v1 = *reinterpret_cast<const float4*>(p + 4);
    bf16x8 t;
    t[0] = (__bf16)v0.x; t[1] = (__bf16)v0.y; t[2] = (__bf16)v0.z; t[3] = (__bf16)v0.w;
    t[4] = (__bf16)v1.x; t[5] = (__bf16)v1.y; t[6] = (__bf16)v1.z; t[7] = (__bf16)v1.w;
    return t;
}

__global__ void k_count(const int* __restrict__ ei, int* __restrict__ cnt) {
    int e = blockIdx.x * blockDim.x + threadIdx.x;
    if (e < N_EDGES) atomicAdd(&cnt[ei[N_EDGES + e]], 1);
}

__global__ void k_scan(const int* __restrict__ cnt, int* __restrict__ row_ptr) {
    __shared__ int sums[1024];
    int t = threadIdx.x;
    const int CH = 10;
    int base = t * CH;
    int s = 0;
    for (int i = 0; i < CH; i++) {
        int n = base + i;
        if (n < N_NODES) s += cnt[n] + 1;   /* +1 self loop */
    }
    sums[t] = s;
    __syncthreads();
    for (int off = 1; off < 1024; off <<= 1) {
        int v = (t >= off) ? sums[t - off] : 0;
        __syncthreads();
        sums[t] += v;
        __syncthreads();
    }
    int run = (t == 0) ? 0 : sums[t - 1];
    for (int i = 0; i < CH; i++) {
        int n = base + i;
        if (n < N_NODES) { row_ptr[n] = run; run += cnt[n] + 1; }
    }
    if (t == 1023) row_ptr[N_NODES] = sums[1023];
}

__global__ void k_fill(const int* __restrict__ ei, const int* __restrict__ row_ptr,
                       int* __restrict__ fill, int* __restrict__ eids,
                       int* __restrict__ sdv, int* __restrict__ pose) {
    int e = blockIdx.x * blockDim.x + threadIdx.x;
    if (e >= NE_TOT) return;
    int s, d;
    if (e < N_EDGES) { s = ei[e]; d = ei[N_EDGES + e]; }
    else             { s = e - N_EDGES; d = s; }
    int pos = atomicAdd(&fill[d], 1);
    int p = row_ptr[d] + pos;
    eids[p] = e;
    sdv[p] = s | (d << 16);
    pose[e] = p;
}

/* sequential read of edge_attr (full-BW stream), bf16 convert, scatter-write
   into CSR order. */
__global__ void k_permute_e(const float* __restrict__ edge_attr,
                            const int* __restrict__ pose,
                            unsigned short* __restrict__ eac) {
    int idx = blockIdx.x * blockDim.x + threadIdx.x;   /* E*32 threads */
    if (idx >= N_EDGES * 32) return;
    int e = idx >> 5, cp = idx & 31;
    float2 v = reinterpret_cast<const float2*>(edge_attr)[(size_t)e * 32 + cp];
    int p = pose[e];
    unsigned int u = ((unsigned int)f2bf(v.x)) | (((unsigned int)f2bf(v.y)) << 16);
    reinterpret_cast<unsigned int*>(eac)[(size_t)p * 32 + cp] = u;
}

/* one wave per node: mean of incoming rows (read sequentially from ea_csr),
   written into the self-loop slot.  lane = column. */
__global__ void k_self_attr(const int* __restrict__ row_ptr,
                            const int* __restrict__ pose,
                            unsigned short* __restrict__ eac) {
    int node = (blockIdx.x << 2) + (threadIdx.x >> 6);
    int lane = threadIdx.x & 63;
    int b = row_ptr[node], en = row_ptr[node + 1];
    int selfp = pose[N_EDGES + node];
    float s0 = 0.0f, s1 = 0.0f;
    int i = b;
    for (; i + 1 < en; i += 2) {
        float a0 = bf2f(eac[(size_t)(i + 0) * 64 + lane]);
        float a1 = bf2f(eac[(size_t)(i + 1) * 64 + lane]);
        s0 += (i + 0 == selfp) ? 0.0f : a0;
        s1 += (i + 1 == selfp) ? 0.0f : a1;
    }
    for (; i < en; i++) {
        float a = bf2f(eac[(size_t)i * 64 + lane]);
        s0 += (i == selfp) ? 0.0f : a;
    }
    float s = s0 + s1;
    float c = (float)(en - b - 1);
    eac[(size_t)selfp * 64 + lane] = f2bf(s / fmaxf(c, 1.0f));
}

/* convert Wl/Wr (fp32 [c=256][k=256]) and We (fp32 [c=256][k=64]) to bf16
   MFMA A-fragment order. */
__global__ void k_prep_wfrag(const float* __restrict__ Wl,
                             const float* __restrict__ Wr,
                             const float* __restrict__ We,
                             unsigned short* __restrict__ wlf,
                             unsigned short* __restrict__ wrf,
                             unsigned short* __restrict__ wef) {
    int idx = blockIdx.x * 256 + threadIdx.x;
    if (idx >= 8192) return;
    int ln = idx & 63;
    int ts = (idx >> 6) & 7;
    int ct = idx >> 9;
    int c = ct * 16 + (ln & 15);
    int k0 = ts * 32 + (ln >> 4) * 8;
    *reinterpret_cast<bf16x8*>(wlf + (size_t)idx * 8) = cvt8(Wl + (size_t)c * 256 + k0);
    *reinterpret_cast<bf16x8*>(wrf + (size_t)idx * 8) = cvt8(Wr + (size_t)c * 256 + k0);
    if (idx < 2048) {
        int f = idx >> 6;
        int cb = f >> 1, step = f & 1;
        int ce = cb * 16 + (ln & 15);
        int ke = step * 32 + (ln >> 4) * 8;
        *reinterpret_cast<bf16x8*>(wef + (size_t)idx * 8) = cvt8(We + (size_t)ce * 64 + ke);
    }
}

/* xl/xr projection on MFMA. */
__global__ __launch_bounds__(256) void k_gemm_mfma(
        const float* __restrict__ x,
        const float* __restrict__ bl, const float* __restrict__ br,
        const unsigned short* __restrict__ wlf,
        const unsigned short* __restrict__ wrf,
        unsigned short* __restrict__ xlh,
        unsigned short* __restrict__ xrh) {
    __shared__ __bf16 xs[8 * 64 * 8];   /* [t][lane][8], 8 KB */
    int tid = threadIdx.x;
    int nb = blockIdx.x * 16;

    for (int f = tid; f < 512; f += 256) {
        int t = f >> 6, ln = f & 63;
        int node = nb + (ln & 15);
        int k0 = t * 32 + (ln >> 4) * 8;
        *reinterpret_cast<bf16x8*>(&xs[f * 8]) = cvt8(x + (size_t)node * 256 + k0);
    }
    __syncthreads();

    int lane = tid & 63;
    int wv = tid >> 6;
    int quad = lane >> 4;
    int ln15 = lane & 15;

    bf16x8 bfr[8];
#pragma unroll
    for (int t = 0; t < 8; t++)
        bfr[t] = *reinterpret_cast<const bf16x8*>(&xs[(t * 64 + lane) * 8]);

    int node = nb + ln15;
#pragma unroll
    for (int ci = 0; ci < 4; ci++) {
        int ct = wv * 4 + ci;
        f32x4 accl, accr;
        accl[0] = accl[1] = accl[2] = accl[3] = 0.0f;
        accr[0] = accr[1] = accr[2] = accr[3] = 0.0f;
#pragma unroll
        for (int t = 0; t < 8; t++) {
            bf16x8 al = *reinterpret_cast<const bf16x8*>(
                wlf + ((size_t)(ct * 8 + t) * 64 + lane) * 8);
            accl = __builtin_amdgcn_mfma_f32_16x16x32_bf16(al, bfr[t], accl, 0, 0, 0);
        }
#pragma unroll
        for (int t = 0; t < 8; t++) {
            bf16x8 ar = *reinterpret_cast<const bf16x8*>(
                wrf + ((size_t)(ct * 8 + t) * 64 + lane) * 8);
            accr = __builtin_amdgcn_mfma_f32_16x16x32_bf16(ar, bfr[t], accr, 0, 0, 0);
        }
        int cbase = ct * 16 + quad * 4;
        float4 blv = *reinterpret_cast<const float4*>(bl + cbase);
        float4 brv = *reinterpret_cast<const float4*>(br + cbase);
        us4 ol, orr;
        ol[0] = f2bf(accl[0] + blv.x); ol[1] = f2bf(accl[1] + blv.y);
        ol[2] = f2bf(accl[2] + blv.z); ol[3] = f2bf(accl[3] + blv.w);
        orr[0] = f2bf(accr[0] + brv.x); orr[1] = f2bf(accr[1] + brv.y);
        orr[2] = f2bf(accr[2] + brv.z); orr[3] = f2bf(accr[3] + brv.w);
        *reinterpret_cast<us4*>(xlh + (size_t)node * 256 + cbase) = ol;
        *reinterpret_cast<us4*>(xrh + (size_t)node * 256 + cbase) = orr;
    }
}

/* edge projection epc = We * eac for ALL CSR rows: pure streaming GEMM.
   Contiguous reads (eac in CSR order), weights in LDS, contiguous-ish
   scatter stores per C fragment.  No gathers -> latency fully hidable. */
__global__ __launch_bounds__(256) void k_ep_gemm(
        const unsigned short* __restrict__ eac,
        const unsigned short* __restrict__ wef,
        unsigned short* __restrict__ epc) {
    __shared__ __bf16 wef_s[2048 * 8];   /* 32 KB */
    int tid = threadIdx.x;
    for (int f = tid; f < 2048; f += 256) {
        *reinterpret_cast<bf16x8*>(&wef_s[(size_t)f * 8]) =
            *reinterpret_cast<const bf16x8*>(wef + (size_t)f * 8);
    }
    __syncthreads();

    int lane = tid & 63;
    int wv = tid >> 6;
    int quad = lane >> 4;
    int ln15 = lane & 15;

    const int ntiles = NE_TOT / 16;   /* 20625 */
#pragma unroll 1
    for (int t = blockIdx.x * 4 + wv; t < ntiles; t += gridDim.x * 4) {
        int pos = t * 16 + ln15;
        const unsigned short* row = eac + (size_t)pos * 64;
        bf16x8 b0 = *reinterpret_cast<const bf16x8*>(row + quad * 8);
        bf16x8 b1 = *reinterpret_cast<const bf16x8*>(row + 32 + quad * 8);
        unsigned short* orow = epc + (size_t)pos * 256;
#pragma unroll
        for (int cb = 0; cb < 16; cb++) {
            f32x4 acc;
            acc[0] = acc[1] = acc[2] = acc[3] = 0.0f;
            bf16x8 a0 = *reinterpret_cast<const bf16x8*>(
                &wef_s[((size_t)(cb * 2 + 0) * 64 + lane) * 8]);
            bf16x8 a1 = *reinterpret_cast<const bf16x8*>(
                &wef_s[((size_t)(cb * 2 + 1) * 64 + lane) * 8]);
            acc = __builtin_amdgcn_mfma_f32_16x16x32_bf16(a0, b0, acc, 0, 0, 0);
            acc = __builtin_amdgcn_mfma_f32_16x16x32_bf16(a1, b1, acc, 0, 0, 0);
            us4 o;
            o[0] = f2bf(acc[0]); o[1] = f2bf(acc[1]);
            o[2] = f2bf(acc[2]); o[3] = f2bf(acc[3]);
            *reinterpret_cast<us4*>(orow + cb * 16 + quad * 4) = o;
        }
    }
}

/* per-edge logit: 4 channels/lane, reduce over the 16 lanes of each h-group */
__device__ __forceinline__ float edge_logit(uint2 xlv, uint2 epv,
        float xra, float xrb, float xrc, float xrd, float4 atv) {
    float v0 = lo2f(xlv.x) + xra + lo2f(epv.x); v0 = fmaxf(v0, NEG_SLOPE * v0);
    float v1 = hi2f(xlv.x) + xrb + hi2f(epv.x); v1 = fmaxf(v1, NEG_SLOPE * v1);
    float v2 = lo2f(xlv.y) + xrc + lo2f(epv.y); v2 = fmaxf(v2, NEG_SLOPE * v2);
    float v3 = hi2f(xlv.y) + xrd + hi2f(epv.y); v3 = fmaxf(v3, NEG_SLOPE * v3);
    float hs = fmaf(v0, atv.x, fmaf(v1, atv.y, fmaf(v2, atv.z, v3 * atv.w)));
    hs += __shfl_xor(hs, 1, 64);
    hs += __shfl_xor(hs, 2, 64);
    hs += __shfl_xor(hs, 4, 64);
    hs += __shfl_xor(hs, 8, 64);
    return hs;   /* valid in all 16 lanes of the h-group */
}

/* ONE wave per node: logits (coalesced row gathers) + segment softmax +
   weighted sum + bias + SiLU + LayerNorm, all fused.  lane = 4 channels,
   h = lane>>4.  xr[node] read once; per edge xl[s]/epc[pos] are single
   coalesced 512B wave reads (vs 32 scattered gathers in the old design).
   Logits staged in per-wave LDS (<=256 edges; global fallback above). */
__global__ __launch_bounds__(256) void k_node_fused(
        const int* __restrict__ sdv,
        const int* __restrict__ row_ptr,
        const int* __restrict__ eids,
        const unsigned short* __restrict__ epc,
        const unsigned short* __restrict__ xlh,
        const unsigned short* __restrict__ xrh,
        const float* __restrict__ att,
        const float* __restrict__ bias,
        const float* __restrict__ gamma,
        const float* __restrict__ beta,
        float* __restrict__ lbuf,
        float* __restrict__ hout,
        float* __restrict__ alpha_out) {
    __shared__ float lsc[4][1024];   /* [wave][(edge-in-run)*4 + h], 16 KB */
    int tid = threadIdx.x;
    int wv = tid >> 6, lane = tid & 63;
    int node = blockIdx.x * 4 + wv;
    int h = lane >> 4, l15 = lane & 15;
    int b = row_ptr[node], en = row_ptr[node + 1];
    int len = en - b;
    bool big = len > 256;
    float* ls = lsc[wv];

    const uint2* xl2 = reinterpret_cast<const uint2*>(xlh);
    const uint2* ep2 = reinterpret_cast<const uint2*>(epc);
    float4 atv = reinterpret_cast<const float4*>(att)[lane];
    uint2 xrv = reinterpret_cast<const uint2*>(xrh)[(size_t)node * 64 + lane];
    float xra = lo2f(xrv.x), xrb = hi2f(xrv.x);
    float xrc = lo2f(xrv.y), xrd = hi2f(xrv.y);

    /* ---- pass 1: logits ---- */
    int i = b;
    for (; i + 1 < en; i += 2) {
        int sd0 = sdv[i], sd1 = sdv[i + 1];
        int s0 = sd0 & 0xFFFF, s1 = sd1 & 0xFFFF;
        uint2 xl0 = xl2[(size_t)s0 * 64 + lane];
        uint2 e0v = ep2[(size_t)i * 64 + lane];
        uint2 xl1 = xl2[(size_t)s1 * 64 + lane];
        uint2 e1v = ep2[(size_t)(i + 1) * 64 + lane];
        float h0 = edge_logit(xl0, e0v, xra, xrb, xrc, xrd, atv);
        float h1 = edge_logit(xl1, e1v, xra, xrb, xrc, xrd, atv);
        if (l15 == 0) {
            if (!big) {
                ls[(i - b) * 4 + h] = h0;
                ls[(i + 1 - b) * 4 + h] = h1;
            } else {
                lbuf[(size_t)i * 4 + h] = h0;
                lbuf[(size_t)(i + 1) * 4 + h] = h1;
            }
        }
    }
    if (i < en) {
        int sd0 = sdv[i];
        int s0 = sd0 & 0xFFFF;
        uint2 xl0 = xl2[(size_t)s0 * 64 + lane];
        uint2 e0v = ep2[(size_t)i * 64 + lane];
        float h0 = edge_logit(xl0, e0v, xra, xrb, xrc, xrd, atv);
        if (l15 == 0) {
            if (!big) ls[(i - b) * 4 + h] = h0;
            else      lbuf[(size_t)i * 4 + h] = h0;
        }
    }

    /* ---- softmax stats over the run (16 lanes of each h cooperate) ---- */
    float mh = -INFINITY;
    for (int j = l15; j < len; j += 16) {
        float lg = big ? lbuf[(size_t)(b + j) * 4 + h] : ls[j * 4 + h];
        mh = fmaxf(mh, lg);
    }
    mh = fmaxf(mh, __shfl_xor(mh, 1, 64));
    mh = fmaxf(mh, __shfl_xor(mh, 2, 64));
    mh = fmaxf(mh, __shfl_xor(mh, 4, 64));
    mh = fmaxf(mh, __shfl_xor(mh, 8, 64));
    float den = 0.0f;
    for (int j = l15; j < len; j += 16) {
        float lg = big ? lbuf[(size_t)(b + j) * 4 + h] : ls[j * 4 + h];
        den += __expf(lg - mh);
    }
    den += __shfl_xor(den, 1, 64);
    den += __shfl_xor(den, 2, 64);
    den += __shfl_xor(den, 4, 64);
    den += __shfl_xor(den, 8, 64);
    float rden = 1.0f / den;

    /* ---- pass 2: alpha + weighted sum (xl rows L2-hot from pass 1) ---- */
    float acx = 0.0f, acy = 0.0f, acz = 0.0f, acw = 0.0f;
    i = b;
    for (; i + 1 < en; i += 2) {
        int sd0 = sdv[i], sd1 = sdv[i + 1];
        int e0 = eids[i], e1 = eids[i + 1];
        int s0 = sd0 & 0xFFFF, s1 = sd1 & 0xFFFF;
        uint2 xl0 = xl2[(size_t)s0 * 64 + lane];
        uint2 xl1 = xl2[(size_t)s1 * 64 + lane];
        float lg0 = big ? lbuf[(size_t)i * 4 + h]       : ls[(i - b) * 4 + h];
        float lg1 = big ? lbuf[(size_t)(i + 1) * 4 + h] : ls[(i + 1 - b) * 4 + h];
        float a0 = __expf(lg0 - mh) * rden;
        float a1 = __expf(lg1 - mh) * rden;
        if (l15 == 0) {
            alpha_out[(size_t)e0 * 4 + h] = a0;
            alpha_out[(size_t)e1 * 4 + h] = a1;
        }
        acx = fmaf(a0, lo2f(xl0.x), acx); acy = fmaf(a0, hi2f(xl0.x), acy);
        acz = fmaf(a0, lo2f(xl0.y), acz); acw = fmaf(a0, hi2f(xl0.y), acw);
        acx = fmaf(a1, lo2f(xl1.x), acx); acy = fmaf(a1, hi2f(xl1.x), acy);
        acz = fmaf(a1, lo2f(xl1.y), acz); acw = fmaf(a1, hi2f(xl1.y), acw);
    }
    if (i < en) {
        int sd0 = sdv[i];
        int e0 = eids[i];
        int s0 = sd0 & 0xFFFF;
        uint2 xl0 = xl2[(size_t)s0 * 64 + lane];
        float lg0 = big ? lbuf[(size_t)i * 4 + h] : ls[(i - b) * 4 + h];
        float a0 = __expf(lg0 - mh) * rden;
        if (l15 == 0) alpha_out[(size_t)e0 * 4 + h] = a0;
        acx = fmaf(a0, lo2f(xl0.x), acx); acy = fmaf(a0, hi2f(xl0.x), acy);
        acz = fmaf(a0, lo2f(xl0.y), acz); acw = fmaf(a0, hi2f(xl0.y), acw);
    }

    /* ---- epilogue: bias + SiLU + LayerNorm ---- */
    const float4 b4 = reinterpret_cast<const float4*>(bias)[lane];
    float4 hv;
    hv.x = acx + b4.x; hv.y = acy + b4.y;
    hv.z = acz + b4.z; hv.w = acw + b4.w;
    hv.x = hv.x / (1.0f + __expf(-hv.x));
    hv.y = hv.y / (1.0f + __expf(-hv.y));
    hv.z = hv.z / (1.0f + __expf(-hv.z));
    hv.w = hv.w / (1.0f + __expf(-hv.w));
    float s1 = hv.x + hv.y + hv.z + hv.w;
    float s2 = hv.x * hv.x + hv.y * hv.y + hv.z * hv.z + hv.w * hv.w;
#pragma unroll
    for (int off = 1; off < 64; off <<= 1) {
        s1 += __shfl_xor(s1, off, 64);
        s2 += __shfl_xor(s2, off, 64);
    }
    float mu = s1 * (1.0f / 256.0f);
    float var = s2 * (1.0f / 256.0f) - mu * mu;
    float rs = rsqrtf(var + LN_EPS);
    const float4 g4 = reinterpret_cast<const float4*>(gamma)[lane];
    const float4 be4 = reinterpret_cast<const float4*>(beta)[lane];
    float4 o;
    o.x = (hv.x - mu) * rs * g4.x + be4.x;
    o.y = (hv.y - mu) * rs * g4.y + be4.y;
    o.z = (hv.z - mu) * rs * g4.z + be4.z;
    o.w = (hv.w - mu) * rs * g4.w + be4.w;
    reinterpret_cast<float4*>(hout)[node * 64 + lane] = o;
}

extern "C" void kernel_launch(void* const* d_in, const int* in_sizes, int n_in,
                              void* d_out, int out_size, void* d_ws, size_t ws_size,
                              hipStream_t stream) {
    (void)in_sizes; (void)n_in; (void)out_size; (void)ws_size;
    const float* x         = (const float*)d_in[0];
    const int*   ei        = (const int*)d_in[1];
    const float* edge_attr = (const float*)d_in[2];
    const float* Wl        = (const float*)d_in[3];
    const float* bl        = (const float*)d_in[4];
    const float* Wr        = (const float*)d_in[5];
    const float* br        = (const float*)d_in[6];
    const float* We        = (const float*)d_in[7];
    const float* att       = (const float*)d_in[8];
    const float* bias      = (const float*)d_in[9];
    const float* gamma     = (const float*)d_in[10];
    const float* beta      = (const float*)d_in[11];

    char* ws = (char*)d_ws;
    int*   cnt     = (int*)(ws + OFF_CNT);
    int*   fill    = (int*)(ws + OFF_FILL);
    int*   row_ptr = (int*)(ws + OFF_ROWPTR);
    int*   eids    = (int*)(ws + OFF_EIDS);
    int*   pose    = (int*)(ws + OFF_POSE);
    unsigned short* xlh = (unsigned short*)(ws + OFF_XLH);
    unsigned short* xrh = (unsigned short*)(ws + OFF_XRH);
    float* lbuf    = (float*)(ws + OFF_LOG);
    unsigned short* wlf = (unsigned short*)(ws + OFF_WLF);
    unsigned short* wrf = (unsigned short*)(ws + OFF_WRF);
    unsigned short* wef = (unsigned short*)(ws + OFF_WEF);
    int*   sdv     = (int*)(ws + OFF_SD);
    unsigned short* eac = (unsigned short*)(ws + OFF_EAC);
    unsigned short* epc = (unsigned short*)(ws + OFF_EPC);

    float* hout      = (float*)d_out;
    float* alpha_out = (float*)d_out + N_NODES * 256;

    hipMemsetAsync(ws + OFF_CNT, 0, 2 * N_NODES * sizeof(int), stream);

    k_count<<<(N_EDGES + 255) / 256, 256, 0, stream>>>(ei, cnt);
    k_scan<<<1, 1024, 0, stream>>>(cnt, row_ptr);
    k_prep_wfrag<<<32, 256, 0, stream>>>(Wl, Wr, We, wlf, wrf, wef);
    k_fill<<<(NE_TOT + 255) / 256, 256, 0, stream>>>(ei, row_ptr, fill, eids, sdv, pose);
    k_gemm_mfma<<<N_NODES / 16, 256, 0, stream>>>(x, bl, br, wlf, wrf, xlh, xrh);
    k_permute_e<<<(N_EDGES * 32) / 256, 256, 0, stream>>>(edge_attr, pose, eac);
    k_self_attr<<<N_NODES / 4, 256, 0, stream>>>(row_ptr, pose, eac);
    k_ep_gemm<<<1024, 256, 0, stream>>>(eac, wef, epc);
    k_node_fused<<<N_NODES / 4, 256, 0, stream>>>(sdv, row_ptr, eids, epc, xlh, xrh,
                                                  att, bias, gamma, beta, lbuf,
                                                  hout, alpha_out);
}